// Round 3
// baseline (311.381 us; speedup 1.0000x reference)
//
#include <hip/hip_runtime.h>

typedef _Float16 f16;
typedef _Float16 f16x4 __attribute__((ext_vector_type(4)));
typedef _Float16 f16x8 __attribute__((ext_vector_type(8)));
typedef float    f32x4 __attribute__((ext_vector_type(4)));

#define MFMA_F16(a,b,c) __builtin_amdgcn_mfma_f32_16x16x32_f16((a),(b),(c),0,0,0)

static constexpr int B_  = 2;
static constexpr int S_  = 2048;
static constexpr int D_  = 2048;
static constexpr int H_  = 16;
static constexpr int DK_ = 128;
static constexpr int K_  = 2048;   // GEMM inner dim for both GEMMs
static constexpr int NKT = K_ / 32;  // 64 K-steps of BK=32

__device__ __forceinline__ void gload_lds16(const void* g, void* l) {
  __builtin_amdgcn_global_load_lds(
      (const __attribute__((address_space(1))) void*)g,
      (__attribute__((address_space(3))) void*)l, 16, 0, 0);
}

// ---------------- cast f32 -> f16 ----------------
__global__ __launch_bounds__(256) void cast_f16_kernel(const float* __restrict__ in,
                                                       f16* __restrict__ out, int n4) {
  int i = blockIdx.x * 256 + threadIdx.x;
  int stride = gridDim.x * 256;
  for (int j = i; j < n4; j += stride) {
    float4 v = reinterpret_cast<const float4*>(in)[j];
    f16x4 o = {(f16)v.x, (f16)v.y, (f16)v.z, (f16)v.w};
    reinterpret_cast<f16x4*>(out)[j] = o;
  }
}

// ============ ring-pipelined GEMM core (128x128 tile, BK=32, ring-4 LDS) ============
// LDS tile layout (per ring slot, 16KB): A 8KB then B 8KB.
//   A: [rb=0..7][rr=0..15][kg=0..3][8 f16]   (rb = 16-row block; kg = 8-f16 k-group)
// Fragment read for (rb): wave reads contiguous 1KB at rb*1024 + (lr*4+lg)*16 -> conflict-free.
// Staged via global_load_lds (linear dest = base + lane*16) with the SOURCE permuted to match:
//   lane l fetches global (row = rb*16 + (l>>2), kcols = kt*32 + (l&3)*8 .. +8).

__device__ __forceinline__ void ring_stage(const f16* gA0, const f16* gA1,
                                           const f16* gB0, const f16* gB1,
                                           int tt, char* lds, int w) {
  char* base = lds + (tt & 3) * 16384;
  gload_lds16(gA0 + tt * 32, base +         w * 1024);
  gload_lds16(gA1 + tt * 32, base +  4096 + w * 1024);
  gload_lds16(gB0 + tt * 32, base +  8192 + w * 1024);
  gload_lds16(gB1 + tt * 32, base + 12288 + w * 1024);
}

__device__ __forceinline__ void ring_step(const char* base, int wr, int wc, int lr, int lg,
                                          f32x4 (&acc)[4][4]) {
  f16x8 af[4], bf[4];
#pragma unroll
  for (int mi = 0; mi < 4; ++mi)
    af[mi] = *(const f16x8*)(base + (wr * 4 + mi) * 1024 + (lr * 4 + lg) * 16);
#pragma unroll
  for (int ni = 0; ni < 4; ++ni)
    bf[ni] = *(const f16x8*)(base + 8192 + (wc * 4 + ni) * 1024 + (lr * 4 + lg) * 16);
#pragma unroll
  for (int mi = 0; mi < 4; ++mi)
#pragma unroll
    for (int ni = 0; ni < 4; ++ni)
      acc[mi][ni] = MFMA_F16(af[mi], bf[ni], acc[mi][ni]);
}

#define RING_SYNC(N)                                          \
  asm volatile("s_waitcnt vmcnt(" #N ")" ::: "memory");       \
  __builtin_amdgcn_s_barrier();                               \
  asm volatile("" ::: "memory");

__device__ __forceinline__ void gemm_core_ring(const f16* __restrict__ A,
                                               const f16* __restrict__ Bw,
                                               int brow, int bcol, char* lds,
                                               f32x4 (&acc)[4][4]) {
  const int tid = threadIdx.x;
  const int w = tid >> 6, l = tid & 63;
  const int lg = l >> 4, lr = l & 15;
  const int wr = w >> 1, wc = w & 1;
  const int srow = l >> 2;            // row within 16-row block
  const int scol = (l & 3) * 8;       // f16 col within the 32-wide K-step

#pragma unroll
  for (int mi = 0; mi < 4; ++mi)
#pragma unroll
    for (int ni = 0; ni < 4; ++ni) acc[mi][ni] = (f32x4){0.f, 0.f, 0.f, 0.f};

  const f16* gA0 = A  + (size_t)(brow * 128 + w * 16 + srow) * K_ + scol;
  const f16* gA1 = gA0 + (size_t)64 * K_;
  const f16* gB0 = Bw + (size_t)(bcol * 128 + w * 16 + srow) * K_ + scol;
  const f16* gB1 = gB0 + (size_t)64 * K_;

  // prologue: stage tiles 0,1,2 (12 loads/wave); wait so tile 0 is landed everywhere
  ring_stage(gA0, gA1, gB0, gB1, 0, lds, w);
  ring_stage(gA0, gA1, gB0, gB1, 1, lds, w);
  ring_stage(gA0, gA1, gB0, gB1, 2, lds, w);
  RING_SYNC(8)

  // main loop: stage t+3, compute t, keep 2 tiles in flight (vmcnt(8), never 0)
#pragma unroll 4
  for (int t = 0; t < NKT - 4; ++t) {
    ring_stage(gA0, gA1, gB0, gB1, t + 3, lds, w);
    ring_step(lds + (t & 3) * 16384, wr, wc, lr, lg, acc);
    RING_SYNC(8)
  }
  // t = NKT-4: last stage
  ring_stage(gA0, gA1, gB0, gB1, NKT - 1, lds, w);
  ring_step(lds + ((NKT - 4) & 3) * 16384, wr, wc, lr, lg, acc);
  RING_SYNC(8)
  // t = NKT-3
  ring_step(lds + ((NKT - 3) & 3) * 16384, wr, wc, lr, lg, acc);
  RING_SYNC(4)
  // t = NKT-2
  ring_step(lds + ((NKT - 2) & 3) * 16384, wr, wc, lr, lg, acc);
  RING_SYNC(0)
  // t = NKT-1 (no stage, no wait needed after)
  ring_step(lds + ((NKT - 1) & 3) * 16384, wr, wc, lr, lg, acc);
}

// ---------------- GEMM 1: qkv = x @ Wqkv^T, epilogue splits into Q(scaled)/K/V [B,H,S,DK] f16
__global__ __launch_bounds__(256, 2) void gemm_qkv_kernel(const f16* __restrict__ xb,
                                                          const f16* __restrict__ wqkv,
                                                          f16* __restrict__ Q,
                                                          f16* __restrict__ Kk,
                                                          f16* __restrict__ V) {
  __shared__ __align__(16) char lds[65536];
  const int bid = blockIdx.x;
  const int swz = (bid & 7) * 192 + (bid >> 3);  // 1536 % 8 == 0 -> bijective
  const int brow = swz / 48, bcol = swz % 48;

  f32x4 acc[4][4];
  gemm_core_ring(xb, wqkv, brow, bcol, lds, acc);

  const int tid = threadIdx.x;
  const int w = tid >> 6, l = tid & 63;
  const int lg = l >> 4, lr = l & 15;
  const int wr = w >> 1, wc = w & 1;

  const int which = bcol / 16;         // 0:q 1:k 2:v  (128-col tiles never cross)
  const int h = bcol % 16;             // head, constant per block
  f16* outp = (which == 0) ? Q : ((which == 1) ? Kk : V);
  const float scale = (which == 0) ? 0.08838834764831845f : 1.0f;  // 1/sqrt(128)

#pragma unroll
  for (int mi = 0; mi < 4; ++mi) {
    const int mbase = brow * 128 + wr * 64 + mi * 16 + lg * 4;
#pragma unroll
    for (int ni = 0; ni < 4; ++ni) {
      const int dk = wc * 64 + ni * 16 + lr;
#pragma unroll
      for (int r = 0; r < 4; ++r) {
        const int mm = mbase + r;
        const int b = mm >> 11, s = mm & 2047;
        outp[(((size_t)b * H_ + h) * S_ + s) * DK_ + dk] = (f16)(acc[mi][ni][r] * scale);
      }
    }
  }
}

// ---------------- GEMM 2: out = attn @ Wo^T (fp32 out)
__global__ __launch_bounds__(256, 2) void gemm_out_kernel(const f16* __restrict__ ab,
                                                          const f16* __restrict__ wo,
                                                          float* __restrict__ out) {
  __shared__ __align__(16) char lds[65536];
  const int bid = blockIdx.x;
  const int swz = (bid & 7) * 64 + (bid >> 3);
  const int brow = swz / 16, bcol = swz % 16;

  f32x4 acc[4][4];
  gemm_core_ring(ab, wo, brow, bcol, lds, acc);

  const int tid = threadIdx.x;
  const int w = tid >> 6, l = tid & 63;
  const int lg = l >> 4, lr = l & 15;
  const int wr = w >> 1, wc = w & 1;

#pragma unroll
  for (int mi = 0; mi < 4; ++mi) {
    const int mbase = brow * 128 + wr * 64 + mi * 16 + lg * 4;
#pragma unroll
    for (int ni = 0; ni < 4; ++ni) {
      const int n = bcol * 128 + wc * 64 + ni * 16 + lr;
#pragma unroll
      for (int r = 0; r < 4; ++r)
        out[(size_t)(mbase + r) * D_ + n] = acc[mi][ni][r];
    }
  }
}

// ---------------- V transpose: V[B,H,S,DK] -> Vt[B,H,DK,S]
__global__ __launch_bounds__(256) void transpose_v_kernel(const f16* __restrict__ V,
                                                          f16* __restrict__ Vt) {
  const int bid = blockIdx.x;           // (((bh)*32 + st)*2 + dt)
  const int dt = bid & 1;
  const int st = (bid >> 1) & 31;
  const int bh = bid >> 6;
  __shared__ __align__(16) f16 t[64][72];
  const int tid = threadIdx.x;
#pragma unroll
  for (int i = 0; i < 2; ++i) {
    const int chunk = i * 256 + tid;
    const int row = chunk >> 3, c8 = chunk & 7;
    f16x8 v = *(const f16x8*)(V + ((size_t)bh * S_ + st * 64 + row) * DK_ + dt * 64 + c8 * 8);
    *(f16x8*)&t[row][c8 * 8] = v;
  }
  __syncthreads();
#pragma unroll
  for (int i = 0; i < 2; ++i) {
    const int chunk = i * 256 + tid;
    const int row = chunk >> 3, c8 = chunk & 7;   // row = dk_local
    f16x8 v;
#pragma unroll
    for (int jj = 0; jj < 8; ++jj) v[jj] = t[c8 * 8 + jj][row];
    *(f16x8*)(Vt + ((size_t)bh * DK_ + dt * 64 + row) * S_ + st * 64 + c8 * 8) = v;
  }
}

// ---------------- flash attention (causal), 4 waves x 16 q-rows, KV tiles of 64
// Load-balanced: each block processes q-tile `pr` then q-tile `31-pr`.
__global__ __launch_bounds__(256) void attn_kernel(const f16* __restrict__ Q,
                                                   const f16* __restrict__ Kg,
                                                   const f16* __restrict__ Vt,
                                                   f16* __restrict__ O) {
  __shared__ __align__(16) unsigned char Ks[64 * 256];    // [64][128] f16, XOR-swizzled
  __shared__ __align__(16) unsigned char Vs[128 * 128];   // [128][64] f16, XOR-swizzled
  __shared__ __align__(16) unsigned char Ps[4][16 * 128]; // per-wave [16][64] f16, swizzled

  const int bid = blockIdx.x;
  const int pr = bid & 15;                 // pair index 0..15
  const int h  = (bid >> 4) & 15;
  const int b  = bid >> 8;
  const int bh = b * H_ + h;
  const int tid = threadIdx.x;
  const int w = tid >> 6, l = tid & 63;
  const int lg = l >> 4, lr = l & 15;

  for (int half = 0; half < 2; ++half) {
    const int qt = half ? (31 - pr) : pr;

    // Q fragments in registers (Q pre-scaled by 1/sqrt(dk))
    const f16* Qg = Q + ((size_t)bh * S_ + qt * 64 + w * 16) * DK_;
    f16x8 qf[4];
#pragma unroll
    for (int kd = 0; kd < 4; ++kd)
      qf[kd] = *(const f16x8*)(Qg + (size_t)lr * DK_ + kd * 32 + lg * 8);

    f32x4 o[8];
#pragma unroll
    for (int n = 0; n < 8; ++n) o[n] = (f32x4){0.f, 0.f, 0.f, 0.f};
    float mrun[4] = {-1e30f, -1e30f, -1e30f, -1e30f};
    float lrun[4] = {0.f, 0.f, 0.f, 0.f};

    const int ntiles = qt + 1;
    for (int kt = 0; kt < ntiles; ++kt) {
      __syncthreads();
      // stage K tile [64][128]
      const f16* Kt = Kg + ((size_t)bh * S_ + kt * 64) * DK_;
#pragma unroll
      for (int i = 0; i < 4; ++i) {
        const int chunk = i * 256 + tid;
        const int row = chunk >> 4, c8 = chunk & 15;
        uint4 v = *(const uint4*)(Kt + (size_t)row * DK_ + c8 * 8);
        *(uint4*)(Ks + row * 256 + ((c8 * 16) ^ ((row & 7) << 4))) = v;
      }
      // stage Vt tile [128][64]
      const f16* Vtt = Vt + (size_t)bh * DK_ * S_ + kt * 64;
#pragma unroll
      for (int i = 0; i < 4; ++i) {
        const int chunk = i * 256 + tid;
        const int row = chunk >> 3, c8 = chunk & 7;
        uint4 v = *(const uint4*)(Vtt + (size_t)row * S_ + c8 * 8);
        *(uint4*)(Vs + row * 128 + ((c8 * 16) ^ ((row & 7) << 4))) = v;
      }
      __syncthreads();

      // S = Q K^T  (per wave: 16 rows x 64 cols)
      f32x4 s[4];
#pragma unroll
      for (int j = 0; j < 4; ++j) s[j] = (f32x4){0.f, 0.f, 0.f, 0.f};
#pragma unroll
      for (int j = 0; j < 4; ++j) {
        const int row = j * 16 + lr;
#pragma unroll
        for (int kd = 0; kd < 4; ++kd) {
          f16x8 kf = *(const f16x8*)(Ks + row * 256 + ((kd * 64 + lg * 16) ^ ((row & 7) << 4)));
          s[j] = MFMA_F16(qf[kd], kf, s[j]);
        }
      }
      // causal mask on the diagonal tile
      if (kt == qt) {
#pragma unroll
        for (int j = 0; j < 4; ++j) {
          const int col = j * 16 + lr;
#pragma unroll
          for (int r = 0; r < 4; ++r) {
            const int qrow = w * 16 + lg * 4 + r;
            if (col > qrow) s[j][r] = -1e30f;
          }
        }
      }
      // row max (rows live in 16-lane groups; reduce over lr)
      float scl[4];
#pragma unroll
      for (int r = 0; r < 4; ++r) {
        float m0 = fmaxf(fmaxf(s[0][r], s[1][r]), fmaxf(s[2][r], s[3][r]));
#pragma unroll
        for (int msk = 1; msk < 16; msk <<= 1) m0 = fmaxf(m0, __shfl_xor(m0, msk, 64));
        const float nm = fmaxf(mrun[r], m0);
        scl[r] = __expf(mrun[r] - nm);
        mrun[r] = nm;
      }
      // P = exp(S - m); row sums; P -> LDS (f16, swizzled)
      float rs[4] = {0.f, 0.f, 0.f, 0.f};
#pragma unroll
      for (int j = 0; j < 4; ++j) {
#pragma unroll
        for (int r = 0; r < 4; ++r) {
          const float p = __expf(fmaxf(s[j][r] - mrun[r], -80.f));
          rs[r] += p;
          const int row = lg * 4 + r;
          const int cb = (j * 16 + lr) * 2;
          *(f16*)(Ps[w] + row * 128 + (cb ^ ((row & 7) << 4))) = (f16)p;
        }
      }
#pragma unroll
      for (int r = 0; r < 4; ++r) {
        float t = rs[r];
#pragma unroll
        for (int msk = 1; msk < 16; msk <<= 1) t += __shfl_xor(t, msk, 64);
        lrun[r] = lrun[r] * scl[r] + t;
      }
#pragma unroll
      for (int n = 0; n < 8; ++n)
#pragma unroll
        for (int r = 0; r < 4; ++r) o[n][r] *= scl[r];

      asm volatile("s_waitcnt lgkmcnt(0)" ::: "memory");  // P writes visible to own wave

      // O += P @ V  (B-fragments from transposed-V LDS: contiguous reads)
#pragma unroll
      for (int ks = 0; ks < 2; ++ks) {
        f16x8 pf = *(const f16x8*)(Ps[w] + lr * 128 + ((ks * 64 + lg * 16) ^ ((lr & 7) << 4)));
#pragma unroll
        for (int n = 0; n < 8; ++n) {
          const int row = n * 16 + lr;
          f16x8 vf = *(const f16x8*)(Vs + row * 128 + ((ks * 64 + lg * 16) ^ ((row & 7) << 4)));
          o[n] = MFMA_F16(pf, vf, o[n]);
        }
      }
    }

    // epilogue: normalize and store [bs, h*128+dk] f16
#pragma unroll
    for (int r = 0; r < 4; ++r) {
      const float inv = 1.0f / lrun[r];
      const int srow = qt * 64 + w * 16 + lg * 4 + r;
      f16* op = O + ((size_t)b * S_ + srow) * D_ + h * DK_;
#pragma unroll
      for (int n = 0; n < 8; ++n) op[n * 16 + lr] = (f16)(o[n][r] * inv);
    }
  }
}

extern "C" void kernel_launch(void* const* d_in, const int* in_sizes, int n_in,
                              void* d_out, int out_size, void* d_ws, size_t ws_size,
                              hipStream_t stream) {
  const float* x    = (const float*)d_in[0];
  const float* wqkv = (const float*)d_in[1];
  const float* wo   = (const float*)d_in[2];
  float* out = (float*)d_out;
  char* ws = (char*)d_ws;

  // workspace layout (bytes); lifetimes allow two reuses
  f16* xb     = (f16*)(ws + 0);          // 16 MB, x in f16   (later reused as attn_o)
  f16* wqkvb  = (f16*)(ws + 16777216);   // 24 MB             (later reused as Vt)
  f16* wob    = (f16*)(ws + 41943040);   // 8 MB
  f16* Qb     = (f16*)(ws + 50331648);   // 16 MB [B,H,S,DK], pre-scaled
  f16* Kb     = (f16*)(ws + 67108864);   // 16 MB [B,H,S,DK]
  f16* Vb     = (f16*)(ws + 83886080);   // 16 MB [B,H,S,DK]
  f16* Vtb    = (f16*)(ws + 16777216);   // reuse wqkvb: [B,H,DK,S]
  f16* attn_o = (f16*)(ws + 0);          // reuse xb: [B*S, D]

  cast_f16_kernel<<<2048, 256, 0, stream>>>(x, xb, 8388608 / 4);
  cast_f16_kernel<<<2048, 256, 0, stream>>>(wqkv, wqkvb, 12582912 / 4);
  cast_f16_kernel<<<1024, 256, 0, stream>>>(wo, wob, 4194304 / 4);

  gemm_qkv_kernel<<<1536, 256, 0, stream>>>(xb, wqkvb, Qb, Kb, Vb);
  transpose_v_kernel<<<2048, 256, 0, stream>>>(Vb, Vtb);
  attn_kernel<<<512, 256, 0, stream>>>(Qb, Kb, Vtb, attn_o);
  gemm_out_kernel<<<512, 256, 0, stream>>>(attn_o, wob, out);
}

// Round 4
// 299.753 us; speedup vs baseline: 1.0388x; 1.0388x over previous
//
#include <hip/hip_runtime.h>

typedef _Float16 f16;
typedef _Float16 f16x4 __attribute__((ext_vector_type(4)));
typedef _Float16 f16x8 __attribute__((ext_vector_type(8)));
typedef float    f32x4 __attribute__((ext_vector_type(4)));

#define MFMA_F16(a,b,c) __builtin_amdgcn_mfma_f32_16x16x32_f16((a),(b),(c),0,0,0)

static constexpr int B_  = 2;
static constexpr int S_  = 2048;
static constexpr int D_  = 2048;
static constexpr int H_  = 16;
static constexpr int DK_ = 128;
static constexpr int K_  = 2048;
static constexpr int NKT = 64;   // K-steps of BK=32

__device__ __forceinline__ void gload_lds16(const void* g, void* l) {
  __builtin_amdgcn_global_load_lds(
      (const __attribute__((address_space(1))) void*)g,
      (__attribute__((address_space(3))) void*)l, 16, 0, 0);
}

// ---------------- cast f32 -> f16 ----------------
__global__ __launch_bounds__(256) void cast_f16_kernel(const float* __restrict__ in,
                                                       f16* __restrict__ out, int n4) {
  int i = blockIdx.x * 256 + threadIdx.x;
  int stride = gridDim.x * 256;
  for (int j = i; j < n4; j += stride) {
    float4 v = reinterpret_cast<const float4*>(in)[j];
    f16x4 o = {(f16)v.x, (f16)v.y, (f16)v.z, (f16)v.w};
    reinterpret_cast<f16x4*>(out)[j] = o;
  }
}

// ============ ring-3 pipelined GEMM core (128x128 tile, BK=32, 3x16KB LDS ring) ============
// Slot layout (16KB): A 8KB then B 8KB. Each 8KB = 8 row-blocks of 1KB (16 rows x 32 f16).
// Within a row-block, 16B unit s holds (row = s>>2, kgroup = (s&3) ^ ((s>>3)&3)).
// This permutation makes both the linear gload_lds write and the fragment ds_read_b128
// hit all 32 banks uniformly in every 16-lane group (bank = s%8 covers 0..7).
// Read for lane (lr,lg): slot s = lr*4 + (lg ^ ((lr>>1)&3)).
// Stage source for lane l: row = l>>2, kgroup = (l&3) ^ ((l>>3)&3).

__device__ __forceinline__ void ring_stage3(const f16* gA, const f16* gB, int t,
                                            char* slot, int w) {
  gload_lds16(gA + (size_t)(w * 16) * K_ + t * 32,        slot + w * 1024);
  gload_lds16(gA + (size_t)((w + 4) * 16) * K_ + t * 32,  slot + (w + 4) * 1024);
  gload_lds16(gB + (size_t)(w * 16) * K_ + t * 32,        slot + 8192 + w * 1024);
  gload_lds16(gB + (size_t)((w + 4) * 16) * K_ + t * 32,  slot + 8192 + (w + 4) * 1024);
}

__device__ __forceinline__ void ring_step3(const char* slot, int wr, int wc, int lro,
                                           f32x4 (&acc)[4][4]) {
  f16x8 af[4], bf[4];
#pragma unroll
  for (int mi = 0; mi < 4; ++mi)
    af[mi] = *(const f16x8*)(slot + (wr * 4 + mi) * 1024 + lro);
#pragma unroll
  for (int ni = 0; ni < 4; ++ni)
    bf[ni] = *(const f16x8*)(slot + 8192 + (wc * 4 + ni) * 1024 + lro);
  __builtin_amdgcn_s_setprio(1);
#pragma unroll
  for (int mi = 0; mi < 4; ++mi)
#pragma unroll
    for (int ni = 0; ni < 4; ++ni)
      acc[mi][ni] = MFMA_F16(af[mi], bf[ni], acc[mi][ni]);
  __builtin_amdgcn_s_setprio(0);
}

#define SYNC3(N)                                              \
  asm volatile("s_waitcnt vmcnt(" #N ")" ::: "memory");       \
  __builtin_amdgcn_s_barrier();                               \
  asm volatile("" ::: "memory");

#define STEP3(CS, TT, SS)                                     \
  ring_stage3(gA, gB, (TT), (SS), w);                         \
  ring_step3((CS), wr, wc, lro, acc);                         \
  SYNC3(4)

__device__ __forceinline__ void gemm_core3(const f16* __restrict__ A,
                                           const f16* __restrict__ Bw,
                                           int brow, int bcol, char* lds,
                                           f32x4 (&acc)[4][4]) {
  const int tid = threadIdx.x;
  const int w = tid >> 6, l = tid & 63;
  const int lg = l >> 4, lr = l & 15;
  const int wr = w >> 1, wc = w & 1;
  const int lro = (lr * 4 + (lg ^ ((lr >> 1) & 3))) * 16;

#pragma unroll
  for (int mi = 0; mi < 4; ++mi)
#pragma unroll
    for (int ni = 0; ni < 4; ++ni) acc[mi][ni] = (f32x4){0.f, 0.f, 0.f, 0.f};

  const int kgsrc = (l & 3) ^ ((l >> 3) & 3);
  const f16* gA = A  + (size_t)(brow * 128 + (l >> 2)) * K_ + kgsrc * 8;
  const f16* gB = Bw + (size_t)(bcol * 128 + (l >> 2)) * K_ + kgsrc * 8;

  char* s0 = lds;
  char* s1 = lds + 16384;
  char* s2 = lds + 32768;

  // prologue: stage tiles 0,1; wait so tile 0 is landed for all waves
  ring_stage3(gA, gB, 0, s0, w);
  ring_stage3(gA, gB, 1, s1, w);
  SYNC3(4)

  // main: compute t (slot t%3), stage t+2 (slot (t+2)%3), keep 1 tile in flight
  for (int tb = 0; tb < 20; ++tb) {
    const int t = 3 * tb;
    STEP3(s0, t + 2, s2)
    STEP3(s1, t + 3, s0)
    STEP3(s2, t + 4, s1)
  }
  STEP3(s0, 62, s2)   // t=60
  STEP3(s1, 63, s0)   // t=61
  // t=62
  ring_step3(s2, wr, wc, lro, acc);
  asm volatile("s_waitcnt vmcnt(0)" ::: "memory");
  __builtin_amdgcn_s_barrier();
  asm volatile("" ::: "memory");
  // t=63
  ring_step3(s0, wr, wc, lro, acc);
}

// ---------------- GEMM 1: qkv = x @ Wqkv^T; epilogue -> Q(scaled)/K [B,H,S,DK], V transposed [B,H,DK,S]
__global__ __launch_bounds__(256, 3) void gemm_qkv_kernel(const f16* __restrict__ xb,
                                                          const f16* __restrict__ wqkv,
                                                          f16* __restrict__ Q,
                                                          f16* __restrict__ Kk,
                                                          f16* __restrict__ Vt) {
  __shared__ __align__(16) char lds[49152];
  const int bid = blockIdx.x;
  const int swz = (bid & 7) * 192 + (bid >> 3);  // bijective (1536 % 8 == 0)
  const int brow = swz / 48, bcol = swz % 48;

  f32x4 acc[4][4];
  gemm_core3(xb, wqkv, brow, bcol, lds, acc);

  const int tid = threadIdx.x;
  const int w = tid >> 6, l = tid & 63;
  const int lg = l >> 4, lr = l & 15;
  const int wr = w >> 1, wc = w & 1;

  const int which = bcol / 16;         // 0:q 1:k 2:v
  const int h = bcol % 16;

  if (which == 2) {
    // V: write transposed directly -> Vt[b,h,dk,s]
#pragma unroll
    for (int mi = 0; mi < 4; ++mi) {
      const int mbase = brow * 128 + wr * 64 + mi * 16 + lg * 4;
      const int b = mbase >> 11, s = mbase & 2047;
#pragma unroll
      for (int ni = 0; ni < 4; ++ni) {
        const int dk = wc * 64 + ni * 16 + lr;
        f16x4 v = {(f16)acc[mi][ni][0], (f16)acc[mi][ni][1],
                   (f16)acc[mi][ni][2], (f16)acc[mi][ni][3]};
        *(f16x4*)(Vt + ((size_t)(b * H_ + h) * DK_ + dk) * S_ + s) = v;
      }
    }
  } else {
    f16* outp = (which == 0) ? Q : Kk;
    const float scale = (which == 0) ? 0.08838834764831845f : 1.0f;  // 1/sqrt(128)
#pragma unroll
    for (int mi = 0; mi < 4; ++mi) {
      const int mbase = brow * 128 + wr * 64 + mi * 16 + lg * 4;
#pragma unroll
      for (int ni = 0; ni < 4; ++ni) {
        const int dk = wc * 64 + ni * 16 + lr;
#pragma unroll
        for (int r = 0; r < 4; ++r) {
          const int mm = mbase + r;
          const int b = mm >> 11, s = mm & 2047;
          outp[(((size_t)b * H_ + h) * S_ + s) * DK_ + dk] = (f16)(acc[mi][ni][r] * scale);
        }
      }
    }
  }
}

// ---------------- GEMM 2: out = attn @ Wo^T (fp32 out)
__global__ __launch_bounds__(256, 3) void gemm_out_kernel(const f16* __restrict__ ab,
                                                          const f16* __restrict__ wo,
                                                          float* __restrict__ out) {
  __shared__ __align__(16) char lds[49152];
  const int bid = blockIdx.x;
  const int swz = (bid & 7) * 64 + (bid >> 3);
  const int brow = swz / 16, bcol = swz % 16;

  f32x4 acc[4][4];
  gemm_core3(ab, wo, brow, bcol, lds, acc);

  const int tid = threadIdx.x;
  const int w = tid >> 6, l = tid & 63;
  const int lg = l >> 4, lr = l & 15;
  const int wr = w >> 1, wc = w & 1;

#pragma unroll
  for (int mi = 0; mi < 4; ++mi) {
    const int mbase = brow * 128 + wr * 64 + mi * 16 + lg * 4;
#pragma unroll
    for (int ni = 0; ni < 4; ++ni) {
      const int n = bcol * 128 + wc * 64 + ni * 16 + lr;
#pragma unroll
      for (int r = 0; r < 4; ++r)
        out[(size_t)(mbase + r) * D_ + n] = acc[mi][ni][r];
    }
  }
}

// ---------------- flash attention (causal), 4 waves x 16 q-rows, KV tiles of 64
// Load-balanced: each block processes q-tile `pr` then q-tile `31-pr`.
__global__ __launch_bounds__(256) void attn_kernel(const f16* __restrict__ Q,
                                                   const f16* __restrict__ Kg,
                                                   const f16* __restrict__ Vt,
                                                   f16* __restrict__ O) {
  __shared__ __align__(16) unsigned char Ks[64 * 256];    // [64][128] f16, XOR-swizzled
  __shared__ __align__(16) unsigned char Vs[128 * 128];   // [128][64] f16, XOR-swizzled
  __shared__ __align__(16) unsigned char Ps[4][16 * 128]; // per-wave [16][64] f16, swizzled

  const int bid = blockIdx.x;
  const int pr = bid & 15;                 // pair index 0..15
  const int h  = (bid >> 4) & 15;
  const int b  = bid >> 8;
  const int bh = b * H_ + h;
  const int tid = threadIdx.x;
  const int w = tid >> 6, l = tid & 63;
  const int lg = l >> 4, lr = l & 15;

  for (int half = 0; half < 2; ++half) {
    const int qt = half ? (31 - pr) : pr;

    const f16* Qg = Q + ((size_t)bh * S_ + qt * 64 + w * 16) * DK_;
    f16x8 qf[4];
#pragma unroll
    for (int kd = 0; kd < 4; ++kd)
      qf[kd] = *(const f16x8*)(Qg + (size_t)lr * DK_ + kd * 32 + lg * 8);

    f32x4 o[8];
#pragma unroll
    for (int n = 0; n < 8; ++n) o[n] = (f32x4){0.f, 0.f, 0.f, 0.f};
    float mrun[4] = {-1e30f, -1e30f, -1e30f, -1e30f};
    float lrun[4] = {0.f, 0.f, 0.f, 0.f};

    const int ntiles = qt + 1;
    for (int kt = 0; kt < ntiles; ++kt) {
      __syncthreads();
      // stage K tile [64][128]
      const f16* Kt = Kg + ((size_t)bh * S_ + kt * 64) * DK_;
#pragma unroll
      for (int i = 0; i < 4; ++i) {
        const int chunk = i * 256 + tid;
        const int row = chunk >> 4, c8 = chunk & 15;
        uint4 v = *(const uint4*)(Kt + (size_t)row * DK_ + c8 * 8);
        *(uint4*)(Ks + row * 256 + ((c8 * 16) ^ ((row & 7) << 4))) = v;
      }
      // stage Vt tile [128][64]
      const f16* Vtt = Vt + (size_t)bh * DK_ * S_ + kt * 64;
#pragma unroll
      for (int i = 0; i < 4; ++i) {
        const int chunk = i * 256 + tid;
        const int row = chunk >> 3, c8 = chunk & 7;
        uint4 v = *(const uint4*)(Vtt + (size_t)row * S_ + c8 * 8);
        *(uint4*)(Vs + row * 128 + ((c8 * 16) ^ ((row & 7) << 4))) = v;
      }
      __syncthreads();

      // S = Q K^T
      f32x4 s[4];
#pragma unroll
      for (int j = 0; j < 4; ++j) s[j] = (f32x4){0.f, 0.f, 0.f, 0.f};
      __builtin_amdgcn_s_setprio(1);
#pragma unroll
      for (int j = 0; j < 4; ++j) {
        const int row = j * 16 + lr;
#pragma unroll
        for (int kd = 0; kd < 4; ++kd) {
          f16x8 kf = *(const f16x8*)(Ks + row * 256 + ((kd * 64 + lg * 16) ^ ((row & 7) << 4)));
          s[j] = MFMA_F16(qf[kd], kf, s[j]);
        }
      }
      __builtin_amdgcn_s_setprio(0);
      // causal mask on the diagonal tile
      if (kt == qt) {
#pragma unroll
        for (int j = 0; j < 4; ++j) {
          const int col = j * 16 + lr;
#pragma unroll
          for (int r = 0; r < 4; ++r) {
            const int qrow = w * 16 + lg * 4 + r;
            if (col > qrow) s[j][r] = -1e30f;
          }
        }
      }
      // row max
      float scl[4];
#pragma unroll
      for (int r = 0; r < 4; ++r) {
        float m0 = fmaxf(fmaxf(s[0][r], s[1][r]), fmaxf(s[2][r], s[3][r]));
#pragma unroll
        for (int msk = 1; msk < 16; msk <<= 1) m0 = fmaxf(m0, __shfl_xor(m0, msk, 64));
        const float nm = fmaxf(mrun[r], m0);
        scl[r] = __expf(mrun[r] - nm);
        mrun[r] = nm;
      }
      // P = exp(S - m); row sums; P -> LDS
      float rs[4] = {0.f, 0.f, 0.f, 0.f};
#pragma unroll
      for (int j = 0; j < 4; ++j) {
#pragma unroll
        for (int r = 0; r < 4; ++r) {
          const float p = __expf(fmaxf(s[j][r] - mrun[r], -80.f));
          rs[r] += p;
          const int row = lg * 4 + r;
          const int cb = (j * 16 + lr) * 2;
          *(f16*)(Ps[w] + row * 128 + (cb ^ ((row & 7) << 4))) = (f16)p;
        }
      }
#pragma unroll
      for (int r = 0; r < 4; ++r) {
        float t = rs[r];
#pragma unroll
        for (int msk = 1; msk < 16; msk <<= 1) t += __shfl_xor(t, msk, 64);
        lrun[r] = lrun[r] * scl[r] + t;
      }
#pragma unroll
      for (int n = 0; n < 8; ++n)
#pragma unroll
        for (int r = 0; r < 4; ++r) o[n][r] *= scl[r];

      asm volatile("s_waitcnt lgkmcnt(0)" ::: "memory");

      // O += P @ V
      __builtin_amdgcn_s_setprio(1);
#pragma unroll
      for (int ks = 0; ks < 2; ++ks) {
        f16x8 pf = *(const f16x8*)(Ps[w] + lr * 128 + ((ks * 64 + lg * 16) ^ ((lr & 7) << 4)));
#pragma unroll
        for (int n = 0; n < 8; ++n) {
          const int row = n * 16 + lr;
          f16x8 vf = *(const f16x8*)(Vs + row * 128 + ((ks * 64 + lg * 16) ^ ((row & 7) << 4)));
          o[n] = MFMA_F16(pf, vf, o[n]);
        }
      }
      __builtin_amdgcn_s_setprio(0);
    }

    // epilogue
#pragma unroll
    for (int r = 0; r < 4; ++r) {
      const float inv = 1.0f / lrun[r];
      const int srow = qt * 64 + w * 16 + lg * 4 + r;
      f16* op = O + ((size_t)b * S_ + srow) * D_ + h * DK_;
#pragma unroll
      for (int n = 0; n < 8; ++n) op[n * 16 + lr] = (f16)(o[n][r] * inv);
    }
  }
}

extern "C" void kernel_launch(void* const* d_in, const int* in_sizes, int n_in,
                              void* d_out, int out_size, void* d_ws, size_t ws_size,
                              hipStream_t stream) {
  const float* x    = (const float*)d_in[0];
  const float* wqkv = (const float*)d_in[1];
  const float* wo   = (const float*)d_in[2];
  float* out = (float*)d_out;
  char* ws = (char*)d_ws;

  // workspace layout (bytes)
  f16* xb     = (f16*)(ws + 0);          // 16 MB (reused as attn_o after qkv GEMM)
  f16* wqkvb  = (f16*)(ws + 16777216);   // 24 MB
  f16* wob    = (f16*)(ws + 41943040);   // 8 MB
  f16* Qb     = (f16*)(ws + 50331648);   // 16 MB [B,H,S,DK], pre-scaled
  f16* Kb     = (f16*)(ws + 67108864);   // 16 MB [B,H,S,DK]
  f16* Vtb    = (f16*)(ws + 83886080);   // 16 MB [B,H,DK,S] (written transposed by qkv GEMM)
  f16* attn_o = (f16*)(ws + 0);          // reuse xb: [B*S, D]

  cast_f16_kernel<<<2048, 256, 0, stream>>>(x, xb, 8388608 / 4);
  cast_f16_kernel<<<2048, 256, 0, stream>>>(wqkv, wqkvb, 12582912 / 4);
  cast_f16_kernel<<<1024, 256, 0, stream>>>(wo, wob, 4194304 / 4);

  gemm_qkv_kernel<<<1536, 256, 0, stream>>>(xb, wqkvb, Qb, Kb, Vtb);
  attn_kernel<<<512, 256, 0, stream>>>(Qb, Kb, Vtb, attn_o);
  gemm_out_kernel<<<512, 256, 0, stream>>>(attn_o, wob, out);
}

// Round 5
// 287.353 us; speedup vs baseline: 1.0836x; 1.0432x over previous
//
#include <hip/hip_runtime.h>

typedef _Float16 f16;
typedef _Float16 f16x4 __attribute__((ext_vector_type(4)));
typedef _Float16 f16x8 __attribute__((ext_vector_type(8)));
typedef float    f32x4 __attribute__((ext_vector_type(4)));

#define MFMA_F16(a,b,c) __builtin_amdgcn_mfma_f32_16x16x32_f16((a),(b),(c),0,0,0)

static constexpr int B_  = 2;
static constexpr int S_  = 2048;
static constexpr int D_  = 2048;
static constexpr int H_  = 16;
static constexpr int DK_ = 128;
static constexpr int K_  = 2048;
static constexpr int NKT = 64;   // K-steps of BK=32

__device__ __forceinline__ void gload_lds16(const void* g, void* l) {
  __builtin_amdgcn_global_load_lds(
      (const __attribute__((address_space(1))) void*)g,
      (__attribute__((address_space(3))) void*)l, 16, 0, 0);
}

// ---------------- cast f32 -> f16 ----------------
__global__ __launch_bounds__(256) void cast_f16_kernel(const float* __restrict__ in,
                                                       f16* __restrict__ out, int n4) {
  int i = blockIdx.x * 256 + threadIdx.x;
  int stride = gridDim.x * 256;
  for (int j = i; j < n4; j += stride) {
    float4 v = reinterpret_cast<const float4*>(in)[j];
    f16x4 o = {(f16)v.x, (f16)v.y, (f16)v.z, (f16)v.w};
    reinterpret_cast<f16x4*>(out)[j] = o;
  }
}

// ============ ring-3 pipelined GEMM core (128x128 tile, BK=32, 3x16KB LDS ring) ============
// Slot layout (16KB): A 8KB then B 8KB. Each 8KB = 8 row-blocks of 1KB (16 rows x 32 f16).
// Within a row-block, 16B unit s holds (row = s>>2, kgroup = (s&3) ^ ((s>>3)&3)).
// Conflict-free on both the linear gload_lds write and the fragment ds_read_b128
// (verified: SQ_LDS_BANK_CONFLICT == 0).

__device__ __forceinline__ void ring_stage3(const f16* gA, const f16* gB, int t,
                                            char* slot, int w) {
  gload_lds16(gA + (size_t)(w * 16) * K_ + t * 32,        slot + w * 1024);
  gload_lds16(gA + (size_t)((w + 4) * 16) * K_ + t * 32,  slot + (w + 4) * 1024);
  gload_lds16(gB + (size_t)(w * 16) * K_ + t * 32,        slot + 8192 + w * 1024);
  gload_lds16(gB + (size_t)((w + 4) * 16) * K_ + t * 32,  slot + 8192 + (w + 4) * 1024);
}

__device__ __forceinline__ void ring_step3(const char* slot, int wr, int wc, int lro,
                                           f32x4 (&acc)[4][4]) {
  f16x8 af[4], bf[4];
#pragma unroll
  for (int mi = 0; mi < 4; ++mi)
    af[mi] = *(const f16x8*)(slot + (wr * 4 + mi) * 1024 + lro);
#pragma unroll
  for (int ni = 0; ni < 4; ++ni)
    bf[ni] = *(const f16x8*)(slot + 8192 + (wc * 4 + ni) * 1024 + lro);
  __builtin_amdgcn_s_setprio(1);
#pragma unroll
  for (int mi = 0; mi < 4; ++mi)
#pragma unroll
    for (int ni = 0; ni < 4; ++ni)
      acc[mi][ni] = MFMA_F16(af[mi], bf[ni], acc[mi][ni]);
  __builtin_amdgcn_s_setprio(0);
}

#define SYNC3(N)                                              \
  asm volatile("s_waitcnt vmcnt(" #N ")" ::: "memory");       \
  __builtin_amdgcn_s_barrier();                               \
  asm volatile("" ::: "memory");

#define STEP3(CS, TT, SS)                                     \
  ring_stage3(gA, gB, (TT), (SS), w);                         \
  ring_step3((CS), wr, wc, lro, acc);                         \
  SYNC3(4)

__device__ __forceinline__ void gemm_core3(const f16* __restrict__ A,
                                           const f16* __restrict__ Bw,
                                           int brow, int bcol, char* lds,
                                           f32x4 (&acc)[4][4]) {
  const int tid = threadIdx.x;
  const int w = tid >> 6, l = tid & 63;
  const int lg = l >> 4, lr = l & 15;
  const int wr = w >> 1, wc = w & 1;
  const int lro = (lr * 4 + (lg ^ ((lr >> 1) & 3))) * 16;

#pragma unroll
  for (int mi = 0; mi < 4; ++mi)
#pragma unroll
    for (int ni = 0; ni < 4; ++ni) acc[mi][ni] = (f32x4){0.f, 0.f, 0.f, 0.f};

  const int kgsrc = (l & 3) ^ ((l >> 3) & 3);
  const f16* gA = A  + (size_t)(brow * 128 + (l >> 2)) * K_ + kgsrc * 8;
  const f16* gB = Bw + (size_t)(bcol * 128 + (l >> 2)) * K_ + kgsrc * 8;

  char* s0 = lds;
  char* s1 = lds + 16384;
  char* s2 = lds + 32768;

  // prologue: stage tiles 0,1; wait so tile 0 is landed for all waves
  ring_stage3(gA, gB, 0, s0, w);
  ring_stage3(gA, gB, 1, s1, w);
  SYNC3(4)

  // main: compute t (slot t%3), stage t+2 (slot (t+2)%3), keep 1 tile in flight
  for (int tb = 0; tb < 20; ++tb) {
    const int t = 3 * tb;
    STEP3(s0, t + 2, s2)
    STEP3(s1, t + 3, s0)
    STEP3(s2, t + 4, s1)
  }
  STEP3(s0, 62, s2)   // t=60
  STEP3(s1, 63, s0)   // t=61
  // t=62
  ring_step3(s2, wr, wc, lro, acc);
  asm volatile("s_waitcnt vmcnt(0)" ::: "memory");
  __builtin_amdgcn_s_barrier();
  asm volatile("" ::: "memory");
  // t=63
  ring_step3(s0, wr, wc, lro, acc);
}

// ---------------- GEMM 1: qkv = x @ Wqkv^T; epilogue -> Q(scaled)/K [B,H,S,DK], V transposed [B,H,DK,S]
// XCD-chunked swizzle: grid 32x48; each XCD owns an 8-row x 24-col chunk,
// traversed COLUMN-major so a B panel's 8 consumers are adjacent in dispatch
// order (B fetched ~once per chunk) and the 8 A panels (4MB) stay L2-resident.
__global__ __launch_bounds__(256, 3) void gemm_qkv_kernel(const f16* __restrict__ xb,
                                                          const f16* __restrict__ wqkv,
                                                          f16* __restrict__ Q,
                                                          f16* __restrict__ Kk,
                                                          f16* __restrict__ Vt) {
  __shared__ __align__(16) char lds[49152];
  const int bid = blockIdx.x;
  const int xcd = bid & 7;
  const int local = bid >> 3;                         // 0..191
  const int brow = (xcd >> 1) * 8 + (local & 7);      // 4 chunk-rows of 8
  const int bcol = (xcd & 1) * 24 + (local >> 3);     // 2 chunk-cols of 24, col-major

  f32x4 acc[4][4];
  gemm_core3(xb, wqkv, brow, bcol, lds, acc);

  const int tid = threadIdx.x;
  const int w = tid >> 6, l = tid & 63;
  const int lg = l >> 4, lr = l & 15;
  const int wr = w >> 1, wc = w & 1;

  const int which = bcol / 16;         // 0:q 1:k 2:v
  const int h = bcol % 16;

  if (which == 2) {
    // V: write transposed directly -> Vt[b,h,dk,s]
#pragma unroll
    for (int mi = 0; mi < 4; ++mi) {
      const int mbase = brow * 128 + wr * 64 + mi * 16 + lg * 4;
      const int b = mbase >> 11, s = mbase & 2047;
#pragma unroll
      for (int ni = 0; ni < 4; ++ni) {
        const int dk = wc * 64 + ni * 16 + lr;
        f16x4 v = {(f16)acc[mi][ni][0], (f16)acc[mi][ni][1],
                   (f16)acc[mi][ni][2], (f16)acc[mi][ni][3]};
        *(f16x4*)(Vt + ((size_t)(b * H_ + h) * DK_ + dk) * S_ + s) = v;
      }
    }
  } else {
    f16* outp = (which == 0) ? Q : Kk;
    const float scale = (which == 0) ? 0.08838834764831845f : 1.0f;  // 1/sqrt(128)
#pragma unroll
    for (int mi = 0; mi < 4; ++mi) {
      const int mbase = brow * 128 + wr * 64 + mi * 16 + lg * 4;
#pragma unroll
      for (int ni = 0; ni < 4; ++ni) {
        const int dk = wc * 64 + ni * 16 + lr;
#pragma unroll
        for (int r = 0; r < 4; ++r) {
          const int mm = mbase + r;
          const int b = mm >> 11, s = mm & 2047;
          outp[(((size_t)b * H_ + h) * S_ + s) * DK_ + dk] = (f16)(acc[mi][ni][r] * scale);
        }
      }
    }
  }
}

// ---------------- GEMM 2: out = attn @ Wo^T (fp32 out)
__global__ __launch_bounds__(256, 3) void gemm_out_kernel(const f16* __restrict__ ab,
                                                          const f16* __restrict__ wo,
                                                          float* __restrict__ out) {
  __shared__ __align__(16) char lds[49152];
  const int bid = blockIdx.x;
  const int xcd = bid & 7;
  const int local = bid >> 3;                         // 0..63
  const int brow = (xcd >> 1) * 8 + (local & 7);      // 4 chunk-rows of 8
  const int bcol = (xcd & 1) * 8 + (local >> 3);      // 2 chunk-cols of 8, col-major

  f32x4 acc[4][4];
  gemm_core3(ab, wo, brow, bcol, lds, acc);

  const int tid = threadIdx.x;
  const int w = tid >> 6, l = tid & 63;
  const int lg = l >> 4, lr = l & 15;
  const int wr = w >> 1, wc = w & 1;

#pragma unroll
  for (int mi = 0; mi < 4; ++mi) {
    const int mbase = brow * 128 + wr * 64 + mi * 16 + lg * 4;
#pragma unroll
    for (int ni = 0; ni < 4; ++ni) {
      const int n = bcol * 128 + wc * 64 + ni * 16 + lr;
#pragma unroll
      for (int r = 0; r < 4; ++r)
        out[(size_t)(mbase + r) * D_ + n] = acc[mi][ni][r];
    }
  }
}

// ---------------- flash attention (causal), 4 waves x 16 q-rows, KV tiles of 64
// Load-balanced: each block processes q-tile `pr` then q-tile `31-pr`.
__global__ __launch_bounds__(256) void attn_kernel(const f16* __restrict__ Q,
                                                   const f16* __restrict__ Kg,
                                                   const f16* __restrict__ Vt,
                                                   f16* __restrict__ O) {
  __shared__ __align__(16) unsigned char Ks[64 * 256];    // [64][128] f16, XOR-swizzled
  __shared__ __align__(16) unsigned char Vs[128 * 128];   // [128][64] f16, XOR-swizzled
  __shared__ __align__(16) unsigned char Ps[4][16 * 128]; // per-wave [16][64] f16, swizzled

  const int bid = blockIdx.x;
  const int pr = bid & 15;                 // pair index 0..15
  const int h  = (bid >> 4) & 15;
  const int b  = bid >> 8;
  const int bh = b * H_ + h;
  const int tid = threadIdx.x;
  const int w = tid >> 6, l = tid & 63;
  const int lg = l >> 4, lr = l & 15;

  for (int half = 0; half < 2; ++half) {
    const int qt = half ? (31 - pr) : pr;

    const f16* Qg = Q + ((size_t)bh * S_ + qt * 64 + w * 16) * DK_;
    f16x8 qf[4];
#pragma unroll
    for (int kd = 0; kd < 4; ++kd)
      qf[kd] = *(const f16x8*)(Qg + (size_t)lr * DK_ + kd * 32 + lg * 8);

    f32x4 o[8];
#pragma unroll
    for (int n = 0; n < 8; ++n) o[n] = (f32x4){0.f, 0.f, 0.f, 0.f};
    float mrun[4] = {-1e30f, -1e30f, -1e30f, -1e30f};
    float lrun[4] = {0.f, 0.f, 0.f, 0.f};

    const int ntiles = qt + 1;
    for (int kt = 0; kt < ntiles; ++kt) {
      __syncthreads();
      // stage K tile [64][128]
      const f16* Kt = Kg + ((size_t)bh * S_ + kt * 64) * DK_;
#pragma unroll
      for (int i = 0; i < 4; ++i) {
        const int chunk = i * 256 + tid;
        const int row = chunk >> 4, c8 = chunk & 15;
        uint4 v = *(const uint4*)(Kt + (size_t)row * DK_ + c8 * 8);
        *(uint4*)(Ks + row * 256 + ((c8 * 16) ^ ((row & 7) << 4))) = v;
      }
      // stage Vt tile [128][64]
      const f16* Vtt = Vt + (size_t)bh * DK_ * S_ + kt * 64;
#pragma unroll
      for (int i = 0; i < 4; ++i) {
        const int chunk = i * 256 + tid;
        const int row = chunk >> 3, c8 = chunk & 7;
        uint4 v = *(const uint4*)(Vtt + (size_t)row * S_ + c8 * 8);
        *(uint4*)(Vs + row * 128 + ((c8 * 16) ^ ((row & 7) << 4))) = v;
      }
      __syncthreads();

      // S = Q K^T
      f32x4 s[4];
#pragma unroll
      for (int j = 0; j < 4; ++j) s[j] = (f32x4){0.f, 0.f, 0.f, 0.f};
      __builtin_amdgcn_s_setprio(1);
#pragma unroll
      for (int j = 0; j < 4; ++j) {
        const int row = j * 16 + lr;
#pragma unroll
        for (int kd = 0; kd < 4; ++kd) {
          f16x8 kf = *(const f16x8*)(Ks + row * 256 + ((kd * 64 + lg * 16) ^ ((row & 7) << 4)));
          s[j] = MFMA_F16(qf[kd], kf, s[j]);
        }
      }
      __builtin_amdgcn_s_setprio(0);
      // causal mask on the diagonal tile
      if (kt == qt) {
#pragma unroll
        for (int j = 0; j < 4; ++j) {
          const int col = j * 16 + lr;
#pragma unroll
          for (int r = 0; r < 4; ++r) {
            const int qrow = w * 16 + lg * 4 + r;
            if (col > qrow) s[j][r] = -1e30f;
          }
        }
      }
      // row max
      float scl[4];
#pragma unroll
      for (int r = 0; r < 4; ++r) {
        float m0 = fmaxf(fmaxf(s[0][r], s[1][r]), fmaxf(s[2][r], s[3][r]));
#pragma unroll
        for (int msk = 1; msk < 16; msk <<= 1) m0 = fmaxf(m0, __shfl_xor(m0, msk, 64));
        const float nm = fmaxf(mrun[r], m0);
        scl[r] = __expf(mrun[r] - nm);
        mrun[r] = nm;
      }
      // P = exp(S - m); row sums; P -> LDS
      float rs[4] = {0.f, 0.f, 0.f, 0.f};
#pragma unroll
      for (int j = 0; j < 4; ++j) {
#pragma unroll
        for (int r = 0; r < 4; ++r) {
          const float p = __expf(fmaxf(s[j][r] - mrun[r], -80.f));
          rs[r] += p;
          const int row = lg * 4 + r;
          const int cb = (j * 16 + lr) * 2;
          *(f16*)(Ps[w] + row * 128 + (cb ^ ((row & 7) << 4))) = (f16)p;
        }
      }
#pragma unroll
      for (int r = 0; r < 4; ++r) {
        float t = rs[r];
#pragma unroll
        for (int msk = 1; msk < 16; msk <<= 1) t += __shfl_xor(t, msk, 64);
        lrun[r] = lrun[r] * scl[r] + t;
      }
#pragma unroll
      for (int n = 0; n < 8; ++n)
#pragma unroll
        for (int r = 0; r < 4; ++r) o[n][r] *= scl[r];

      asm volatile("s_waitcnt lgkmcnt(0)" ::: "memory");

      // O += P @ V
      __builtin_amdgcn_s_setprio(1);
#pragma unroll
      for (int ks = 0; ks < 2; ++ks) {
        f16x8 pf = *(const f16x8*)(Ps[w] + lr * 128 + ((ks * 64 + lg * 16) ^ ((lr & 7) << 4)));
#pragma unroll
        for (int n = 0; n < 8; ++n) {
          const int row = n * 16 + lr;
          f16x8 vf = *(const f16x8*)(Vs + row * 128 + ((ks * 64 + lg * 16) ^ ((row & 7) << 4)));
          o[n] = MFMA_F16(pf, vf, o[n]);
        }
      }
      __builtin_amdgcn_s_setprio(0);
    }

    // epilogue
#pragma unroll
    for (int r = 0; r < 4; ++r) {
      const float inv = 1.0f / lrun[r];
      const int srow = qt * 64 + w * 16 + lg * 4 + r;
      f16* op = O + ((size_t)b * S_ + srow) * D_ + h * DK_;
#pragma unroll
      for (int n = 0; n < 8; ++n) op[n * 16 + lr] = (f16)(o[n][r] * inv);
    }
  }
}

extern "C" void kernel_launch(void* const* d_in, const int* in_sizes, int n_in,
                              void* d_out, int out_size, void* d_ws, size_t ws_size,
                              hipStream_t stream) {
  const float* x    = (const float*)d_in[0];
  const float* wqkv = (const float*)d_in[1];
  const float* wo   = (const float*)d_in[2];
  float* out = (float*)d_out;
  char* ws = (char*)d_ws;

  // workspace layout (bytes)
  f16* xb     = (f16*)(ws + 0);          // 16 MB (reused as attn_o after qkv GEMM)
  f16* wqkvb  = (f16*)(ws + 16777216);   // 24 MB
  f16* wob    = (f16*)(ws + 41943040);   // 8 MB
  f16* Qb     = (f16*)(ws + 50331648);   // 16 MB [B,H,S,DK], pre-scaled
  f16* Kb     = (f16*)(ws + 67108864);   // 16 MB [B,H,S,DK]
  f16* Vtb    = (f16*)(ws + 83886080);   // 16 MB [B,H,DK,S] (written transposed by qkv GEMM)
  f16* attn_o = (f16*)(ws + 0);          // reuse xb: [B*S, D]

  cast_f16_kernel<<<2048, 256, 0, stream>>>(x, xb, 8388608 / 4);
  cast_f16_kernel<<<2048, 256, 0, stream>>>(wqkv, wqkvb, 12582912 / 4);
  cast_f16_kernel<<<1024, 256, 0, stream>>>(wo, wob, 4194304 / 4);

  gemm_qkv_kernel<<<1536, 256, 0, stream>>>(xb, wqkvb, Qb, Kb, Vtb);
  attn_kernel<<<512, 256, 0, stream>>>(Qb, Kb, Vtb, attn_o);
  gemm_out_kernel<<<512, 256, 0, stream>>>(attn_o, wob, out);
}

// Round 6
// 269.890 us; speedup vs baseline: 1.1537x; 1.0647x over previous
//
#include <hip/hip_runtime.h>

typedef _Float16 f16;
typedef _Float16 f16x4 __attribute__((ext_vector_type(4)));
typedef _Float16 f16x8 __attribute__((ext_vector_type(8)));
typedef float    f32x4 __attribute__((ext_vector_type(4)));

#define MFMA_F16(a,b,c) __builtin_amdgcn_mfma_f32_16x16x32_f16((a),(b),(c),0,0,0)

static constexpr int B_  = 2;
static constexpr int S_  = 2048;
static constexpr int D_  = 2048;
static constexpr int H_  = 16;
static constexpr int DK_ = 128;
static constexpr int K_  = 2048;

__device__ __forceinline__ void gload_lds16(const void* g, void* l) {
  __builtin_amdgcn_global_load_lds(
      (const __attribute__((address_space(1))) void*)g,
      (__attribute__((address_space(3))) void*)l, 16, 0, 0);
}

// ---------------- cast f32 -> f16 ----------------
__global__ __launch_bounds__(256) void cast_f16_kernel(const float* __restrict__ in,
                                                       f16* __restrict__ out, int n4) {
  int i = blockIdx.x * 256 + threadIdx.x;
  int stride = gridDim.x * 256;
  for (int j = i; j < n4; j += stride) {
    float4 v = reinterpret_cast<const float4*>(in)[j];
    f16x4 o = {(f16)v.x, (f16)v.y, (f16)v.z, (f16)v.w};
    reinterpret_cast<f16x4*>(out)[j] = o;
  }
}

// ============ 128x256 tile, 8-wave, BK=32, ring-4 (4 x 24KB) GEMM core ============
// Slot (24KB): A 8KB (8 row-blocks of 1KB) then B 16KB (16 row-blocks of 1KB).
// Row-block = 16 rows x 4 kgroups x 16B; unit s = rr*4 + (kg ^ ((rr>>1)&3)).
// Conflict-free on linear gload_lds write and ds_read_b128 (verified: conflicts == 0).
// Waves: 2M x 4N -> per-wave 64 rows x 64 cols, acc[4][4].
// Pipeline: stage tile t+3 while computing tile t; s_waitcnt vmcnt(6) per boundary
// (2 tiles = 6 loads/wave stay in flight; never drains to 0 mid-loop).

__device__ __forceinline__ void stage_ph(const f16* gA, const f16* gB, int t,
                                         char* slot, int w) {
  gload_lds16(gA + (size_t)(w * 16) * K_ + t * 32,       slot + w * 1024);
  gload_lds16(gB + (size_t)(w * 16) * K_ + t * 32,       slot + 8192 + w * 1024);
  gload_lds16(gB + (size_t)((w + 8) * 16) * K_ + t * 32, slot + 8192 + (w + 8) * 1024);
}

__device__ __forceinline__ void mfma_ph(const char* slot, int aoff, int boff, int lro,
                                        f32x4 (&acc)[4][4]) {
  f16x8 af[4], bf[4];
#pragma unroll
  for (int mi = 0; mi < 4; ++mi)
    af[mi] = *(const f16x8*)(slot + aoff + mi * 1024 + lro);
#pragma unroll
  for (int ni = 0; ni < 4; ++ni)
    bf[ni] = *(const f16x8*)(slot + boff + ni * 1024 + lro);
  __builtin_amdgcn_s_setprio(1);
#pragma unroll
  for (int mi = 0; mi < 4; ++mi)
#pragma unroll
    for (int ni = 0; ni < 4; ++ni)
      acc[mi][ni] = MFMA_F16(af[mi], bf[ni], acc[mi][ni]);
  __builtin_amdgcn_s_setprio(0);
}

#define SYNCW(N)                                              \
  asm volatile("s_waitcnt vmcnt(" #N ")" ::: "memory");       \
  __builtin_amdgcn_s_barrier();                               \
  asm volatile("" ::: "memory");

__device__ __forceinline__ void gemm_core_w8(const f16* __restrict__ A,
                                             const f16* __restrict__ Bw,
                                             int brow, int bcol, char* lds,
                                             f32x4 (&acc)[4][4]) {
  const int tid = threadIdx.x;
  const int w = tid >> 6, l = tid & 63;
  const int lg = l >> 4, lr = l & 15;
  const int wm = w >> 2, wn = w & 3;
  const int lro = (lr * 4 + (lg ^ ((lr >> 1) & 3))) * 16;
  const int aoff = wm * 4096;
  const int boff = 8192 + wn * 4096;

#pragma unroll
  for (int mi = 0; mi < 4; ++mi)
#pragma unroll
    for (int ni = 0; ni < 4; ++ni) acc[mi][ni] = (f32x4){0.f, 0.f, 0.f, 0.f};

  const int kgsrc = (l & 3) ^ ((l >> 3) & 3);
  const f16* gA = A  + (size_t)(brow * 128 + (l >> 2)) * K_ + kgsrc * 8;
  const f16* gB = Bw + (size_t)(bcol * 256 + (l >> 2)) * K_ + kgsrc * 8;

  char* s0 = lds;
  char* s1 = lds + 24576;
  char* s2 = lds + 49152;
  char* s3 = lds + 73728;

  // prologue: stage tiles 0,1,2 (9 loads/wave); vmcnt(6) -> tile 0 landed everywhere
  stage_ph(gA, gB, 0, s0, w);
  stage_ph(gA, gB, 1, s1, w);
  stage_ph(gA, gB, 2, s2, w);
  SYNCW(6)

  // main: compute t (slot t&3), stage t+3 (slot (t+3)&3); 2 tiles in flight
  for (int tb = 0; tb < 15; ++tb) {
    const int t = tb * 4;
    stage_ph(gA, gB, t + 3, s3, w); mfma_ph(s0, aoff, boff, lro, acc); SYNCW(6)
    stage_ph(gA, gB, t + 4, s0, w); mfma_ph(s1, aoff, boff, lro, acc); SYNCW(6)
    stage_ph(gA, gB, t + 5, s1, w); mfma_ph(s2, aoff, boff, lro, acc); SYNCW(6)
    stage_ph(gA, gB, t + 6, s2, w); mfma_ph(s3, aoff, boff, lro, acc); SYNCW(6)
  }
  // epilogue: t = 60..63
  stage_ph(gA, gB, 63, s3, w); mfma_ph(s0, aoff, boff, lro, acc); SYNCW(6)
  mfma_ph(s1, aoff, boff, lro, acc); SYNCW(3)
  mfma_ph(s2, aoff, boff, lro, acc); SYNCW(0)
  mfma_ph(s3, aoff, boff, lro, acc);
}

// ---------------- GEMM 1: qkv = x @ Wqkv^T; Q(scaled)/K -> [B,H,S,DK], V -> [B,H,DK,S]
// Grid 768 = 32 brow x 24 bcol. XCD chunking: xcd owns brow xcd*4..xcd*4+3, all bcol,
// col-major local order (A chunk 2MB stays L2-resident; B panel shared by 4 rows).
__global__ __launch_bounds__(512) void gemm_qkv_kernel(const f16* __restrict__ xb,
                                                       const f16* __restrict__ wqkv,
                                                       f16* __restrict__ Q,
                                                       f16* __restrict__ Kk,
                                                       f16* __restrict__ Vt) {
  __shared__ __align__(16) char lds[98304];
  const int bid = blockIdx.x;
  const int xcd = bid & 7;
  const int local = bid >> 3;                 // 0..95
  const int brow = xcd * 4 + (local & 3);     // 0..31
  const int bcol = local >> 2;                // 0..23

  f32x4 acc[4][4];
  gemm_core_w8(xb, wqkv, brow, bcol, lds, acc);

  const int tid = threadIdx.x;
  const int w = tid >> 6, l = tid & 63;
  const int lg = l >> 4, lr = l & 15;
  const int wm = w >> 2, wn = w & 3;

  const int which = bcol >> 3;                // 0:q 1:k 2:v (256-col tile never crosses)
  const int nsec = (bcol & 7) * 256;          // col base within section

  if (which == 2) {
    // V: write transposed -> Vt[b,h,dk,s]
#pragma unroll
    for (int mi = 0; mi < 4; ++mi) {
      const int m0 = brow * 128 + wm * 64 + mi * 16 + lg * 4;
      const int b = m0 >> 11, s = m0 & 2047;
#pragma unroll
      for (int ni = 0; ni < 4; ++ni) {
        const int n = nsec + wn * 64 + ni * 16 + lr;
        const int h = n >> 7, dk = n & 127;
        f16x4 v = {(f16)acc[mi][ni][0], (f16)acc[mi][ni][1],
                   (f16)acc[mi][ni][2], (f16)acc[mi][ni][3]};
        *(f16x4*)(Vt + ((size_t)(b * H_ + h) * DK_ + dk) * S_ + s) = v;
      }
    }
  } else {
    f16* outp = (which == 0) ? Q : Kk;
    const float scale = (which == 0) ? 0.08838834764831845f : 1.0f;  // 1/sqrt(128)
#pragma unroll
    for (int mi = 0; mi < 4; ++mi) {
      const int m0 = brow * 128 + wm * 64 + mi * 16 + lg * 4;
#pragma unroll
      for (int ni = 0; ni < 4; ++ni) {
        const int n = nsec + wn * 64 + ni * 16 + lr;
        const int h = n >> 7, dk = n & 127;
#pragma unroll
        for (int r = 0; r < 4; ++r) {
          const int mm = m0 + r;
          const int b = mm >> 11, s = mm & 2047;
          outp[(((size_t)b * H_ + h) * S_ + s) * DK_ + dk] = (f16)(acc[mi][ni][r] * scale);
        }
      }
    }
  }
}

// ---------------- GEMM 2: out = attn @ Wo^T (fp32 out). Grid 256 = 32 x 8, 1 full round.
__global__ __launch_bounds__(512) void gemm_out_kernel(const f16* __restrict__ ab,
                                                       const f16* __restrict__ wo,
                                                       float* __restrict__ out) {
  __shared__ __align__(16) char lds[98304];
  const int bid = blockIdx.x;
  const int xcd = bid & 7;
  const int local = bid >> 3;                 // 0..31
  const int brow = xcd * 4 + (local & 3);     // 0..31
  const int bcol = local >> 2;                // 0..7

  f32x4 acc[4][4];
  gemm_core_w8(ab, wo, brow, bcol, lds, acc);

  const int tid = threadIdx.x;
  const int w = tid >> 6, l = tid & 63;
  const int lg = l >> 4, lr = l & 15;
  const int wm = w >> 2, wn = w & 3;

#pragma unroll
  for (int mi = 0; mi < 4; ++mi) {
    const int m0 = brow * 128 + wm * 64 + mi * 16 + lg * 4;
#pragma unroll
    for (int ni = 0; ni < 4; ++ni) {
      const int n = bcol * 256 + wn * 64 + ni * 16 + lr;
#pragma unroll
      for (int r = 0; r < 4; ++r)
        out[(size_t)(m0 + r) * D_ + n] = acc[mi][ni][r];
    }
  }
}

// ---------------- flash attention (causal), 4 waves x 16 q-rows, KV tiles of 64
// Load-balanced: each block processes q-tile `pr` then q-tile `31-pr`.
__global__ __launch_bounds__(256) void attn_kernel(const f16* __restrict__ Q,
                                                   const f16* __restrict__ Kg,
                                                   const f16* __restrict__ Vt,
                                                   f16* __restrict__ O) {
  __shared__ __align__(16) unsigned char Ks[64 * 256];    // [64][128] f16, XOR-swizzled
  __shared__ __align__(16) unsigned char Vs[128 * 128];   // [128][64] f16, XOR-swizzled
  __shared__ __align__(16) unsigned char Ps[4][16 * 128]; // per-wave [16][64] f16, swizzled

  const int bid = blockIdx.x;
  const int pr = bid & 15;                 // pair index 0..15
  const int h  = (bid >> 4) & 15;
  const int b  = bid >> 8;
  const int bh = b * H_ + h;
  const int tid = threadIdx.x;
  const int w = tid >> 6, l = tid & 63;
  const int lg = l >> 4, lr = l & 15;

  for (int half = 0; half < 2; ++half) {
    const int qt = half ? (31 - pr) : pr;

    const f16* Qg = Q + ((size_t)bh * S_ + qt * 64 + w * 16) * DK_;
    f16x8 qf[4];
#pragma unroll
    for (int kd = 0; kd < 4; ++kd)
      qf[kd] = *(const f16x8*)(Qg + (size_t)lr * DK_ + kd * 32 + lg * 8);

    f32x4 o[8];
#pragma unroll
    for (int n = 0; n < 8; ++n) o[n] = (f32x4){0.f, 0.f, 0.f, 0.f};
    float mrun[4] = {-1e30f, -1e30f, -1e30f, -1e30f};
    float lrun[4] = {0.f, 0.f, 0.f, 0.f};

    const int ntiles = qt + 1;
    for (int kt = 0; kt < ntiles; ++kt) {
      __syncthreads();
      // stage K tile [64][128]
      const f16* Kt = Kg + ((size_t)bh * S_ + kt * 64) * DK_;
#pragma unroll
      for (int i = 0; i < 4; ++i) {
        const int chunk = i * 256 + tid;
        const int row = chunk >> 4, c8 = chunk & 15;
        uint4 v = *(const uint4*)(Kt + (size_t)row * DK_ + c8 * 8);
        *(uint4*)(Ks + row * 256 + ((c8 * 16) ^ ((row & 7) << 4))) = v;
      }
      // stage Vt tile [128][64]
      const f16* Vtt = Vt + (size_t)bh * DK_ * S_ + kt * 64;
#pragma unroll
      for (int i = 0; i < 4; ++i) {
        const int chunk = i * 256 + tid;
        const int row = chunk >> 3, c8 = chunk & 7;
        uint4 v = *(const uint4*)(Vtt + (size_t)row * S_ + c8 * 8);
        *(uint4*)(Vs + row * 128 + ((c8 * 16) ^ ((row & 7) << 4))) = v;
      }
      __syncthreads();

      // S = Q K^T
      f32x4 s[4];
#pragma unroll
      for (int j = 0; j < 4; ++j) s[j] = (f32x4){0.f, 0.f, 0.f, 0.f};
      __builtin_amdgcn_s_setprio(1);
#pragma unroll
      for (int j = 0; j < 4; ++j) {
        const int row = j * 16 + lr;
#pragma unroll
        for (int kd = 0; kd < 4; ++kd) {
          f16x8 kf = *(const f16x8*)(Ks + row * 256 + ((kd * 64 + lg * 16) ^ ((row & 7) << 4)));
          s[j] = MFMA_F16(qf[kd], kf, s[j]);
        }
      }
      __builtin_amdgcn_s_setprio(0);
      // causal mask on the diagonal tile
      if (kt == qt) {
#pragma unroll
        for (int j = 0; j < 4; ++j) {
          const int col = j * 16 + lr;
#pragma unroll
          for (int r = 0; r < 4; ++r) {
            const int qrow = w * 16 + lg * 4 + r;
            if (col > qrow) s[j][r] = -1e30f;
          }
        }
      }
      // row max
      float scl[4];
#pragma unroll
      for (int r = 0; r < 4; ++r) {
        float m0 = fmaxf(fmaxf(s[0][r], s[1][r]), fmaxf(s[2][r], s[3][r]));
#pragma unroll
        for (int msk = 1; msk < 16; msk <<= 1) m0 = fmaxf(m0, __shfl_xor(m0, msk, 64));
        const float nm = fmaxf(mrun[r], m0);
        scl[r] = __expf(mrun[r] - nm);
        mrun[r] = nm;
      }
      // P = exp(S - m); row sums; P -> LDS
      float rs[4] = {0.f, 0.f, 0.f, 0.f};
#pragma unroll
      for (int j = 0; j < 4; ++j) {
#pragma unroll
        for (int r = 0; r < 4; ++r) {
          const float p = __expf(fmaxf(s[j][r] - mrun[r], -80.f));
          rs[r] += p;
          const int row = lg * 4 + r;
          const int cb = (j * 16 + lr) * 2;
          *(f16*)(Ps[w] + row * 128 + (cb ^ ((row & 7) << 4))) = (f16)p;
        }
      }
#pragma unroll
      for (int r = 0; r < 4; ++r) {
        float t = rs[r];
#pragma unroll
        for (int msk = 1; msk < 16; msk <<= 1) t += __shfl_xor(t, msk, 64);
        lrun[r] = lrun[r] * scl[r] + t;
      }
#pragma unroll
      for (int n = 0; n < 8; ++n)
#pragma unroll
        for (int r = 0; r < 4; ++r) o[n][r] *= scl[r];

      asm volatile("s_waitcnt lgkmcnt(0)" ::: "memory");

      // O += P @ V
      __builtin_amdgcn_s_setprio(1);
#pragma unroll
      for (int ks = 0; ks < 2; ++ks) {
        f16x8 pf = *(const f16x8*)(Ps[w] + lr * 128 + ((ks * 64 + lg * 16) ^ ((lr & 7) << 4)));
#pragma unroll
        for (int n = 0; n < 8; ++n) {
          const int row = n * 16 + lr;
          f16x8 vf = *(const f16x8*)(Vs + row * 128 + ((ks * 64 + lg * 16) ^ ((row & 7) << 4)));
          o[n] = MFMA_F16(pf, vf, o[n]);
        }
      }
      __builtin_amdgcn_s_setprio(0);
    }

    // epilogue
#pragma unroll
    for (int r = 0; r < 4; ++r) {
      const float inv = 1.0f / lrun[r];
      const int srow = qt * 64 + w * 16 + lg * 4 + r;
      f16* op = O + ((size_t)b * S_ + srow) * D_ + h * DK_;
#pragma unroll
      for (int n = 0; n < 8; ++n) op[n * 16 + lr] = (f16)(o[n][r] * inv);
    }
  }
}

extern "C" void kernel_launch(void* const* d_in, const int* in_sizes, int n_in,
                              void* d_out, int out_size, void* d_ws, size_t ws_size,
                              hipStream_t stream) {
  const float* x    = (const float*)d_in[0];
  const float* wqkv = (const float*)d_in[1];
  const float* wo   = (const float*)d_in[2];
  float* out = (float*)d_out;
  char* ws = (char*)d_ws;

  // workspace layout (bytes)
  f16* xb     = (f16*)(ws + 0);          // 16 MB (reused as attn_o after qkv GEMM)
  f16* wqkvb  = (f16*)(ws + 16777216);   // 24 MB
  f16* wob    = (f16*)(ws + 41943040);   // 8 MB
  f16* Qb     = (f16*)(ws + 50331648);   // 16 MB [B,H,S,DK], pre-scaled
  f16* Kb     = (f16*)(ws + 67108864);   // 16 MB [B,H,S,DK]
  f16* Vtb    = (f16*)(ws + 83886080);   // 16 MB [B,H,DK,S] (written transposed by qkv GEMM)
  f16* attn_o = (f16*)(ws + 0);          // reuse xb: [B*S, D]

  cast_f16_kernel<<<2048, 256, 0, stream>>>(x, xb, 8388608 / 4);
  cast_f16_kernel<<<2048, 256, 0, stream>>>(wqkv, wqkvb, 12582912 / 4);
  cast_f16_kernel<<<1024, 256, 0, stream>>>(wo, wob, 4194304 / 4);

  gemm_qkv_kernel<<<768, 512, 0, stream>>>(xb, wqkvb, Qb, Kb, Vtb);
  attn_kernel<<<512, 256, 0, stream>>>(Qb, Kb, Vtb, attn_o);
  gemm_out_kernel<<<256, 512, 0, stream>>>(attn_o, wob, out);
}